// Round 1
// baseline (187.898 us; speedup 1.0000x reference)
//
#include <hip/hip_runtime.h>
#include <hip/hip_bf16.h>
#include <math.h>

#define B_   4
#define C_   256
#define H_   96
#define W_   96
#define HW_  (H_ * W_)
#define G_   4
#define CG_  64
#define K_   9
#define PW_  98                            // padded width/height (1-px halo)
#define PROW_ (PW_ * C_)                   // padded row pitch in elems

typedef __bf16  bf16x8 __attribute__((ext_vector_type(8)));
typedef float   f32x4  __attribute__((ext_vector_type(4)));

// ---------------------------------------------------------------------------
// prep:
//  aOW: offset-conv weights, MFMA A order, M padded 18->32:
//    m = mt*16 + (lane&15) (out chan, 0 if >=18); k = ks*32+(lane>>4)*8+j (c)
//  aW: deform weights bf16, MFMA A order:
//    c = ks*32+(lane>>4)*8+j ; co = half*32+ct*16+(lane&15)
// ---------------------------------------------------------------------------
__global__ __launch_bounds__(256) void prep_kernel(
    const float* __restrict__ ow, const float* __restrict__ wt,
    __hip_bfloat16* __restrict__ aOW, __hip_bfloat16* __restrict__ aW)
{
    int idx = blockIdx.x * 256 + threadIdx.x;
    if (idx < 73728) {
        int j    = idx & 7;
        int r    = idx >> 3;
        int lane = r & 63;  r >>= 6;
        int mt   = r & 1;   r >>= 1;
        int ks   = r & 7;   r >>= 3;
        int tap  = r;                     // 0..8
        int m = mt * 16 + (lane & 15);
        int c = ks * 32 + (lane >> 4) * 8 + j;
        float v = (m < 18) ? ow[(m * 256 + c) * 9 + tap] : 0.f;
        aOW[idx] = __float2bfloat16(v);
    }
    if (idx < 147456) {
        int j    = idx & 7;
        int r    = idx >> 3;
        int lane = r & 63;  r >>= 6;
        int ct   = r & 1;   r >>= 1;
        int half = r & 1;   r >>= 1;
        int ks   = r & 1;   r >>= 1;
        int tap  = r % 9;
        int g    = r / 9;
        int c  = ks * 32 + (lane >> 4) * 8 + j;
        int co = half * 32 + ct * 16 + (lane & 15);
        float v = wt[(((g * CG_ + co) * CG_ + c) * 9) + tap];
        aW[idx] = __float2bfloat16(v);
    }
}

// ---------------------------------------------------------------------------
// transpose x (NCHW fp32) -> xtp (padded NHWC bf16, [b][98][98][256], halo=0).
// v2: c-split in half -> 768 blocks (3/CU exactly; v1's 384 blocks = 1.5/CU
// imbalance) and LDS tile 50.7KB -> 25.5KB (6 blocks resident possible).
// ---------------------------------------------------------------------------
__global__ __launch_bounds__(256) void transpose_kernel(
    const float* __restrict__ x, __hip_bfloat16* __restrict__ xtp)
{
    int blk = blockIdx.x;                 // 0..767 = (b*96 + h)*2 + chalf
    int ch  = blk & 1;
    int bh  = blk >> 1;
    int b = bh / H_, h = bh - b * H_;
    int t = threadIdx.x;
    __shared__ __align__(16) __hip_bfloat16 tile[96 * 136];   // [w][128c + 8 pad]
    const float* xb = x + (size_t)b * C_ * HW_ + (size_t)(ch * 128) * HW_ + h * W_;
    for (int r = 0; r < 48; ++r) {
        int e = r * 256 + t;              // 0..12287 = c*96 + w  (c in 0..127)
        int c = e / 96, w = e - c * 96;
        tile[w * 136 + c] = __float2bfloat16(xb[c * HW_ + w]);
    }
    __syncthreads();
    __hip_bfloat16* ob = xtp + ((size_t)(b * PW_ + h + 1) * PW_ + 1) * C_ + ch * 128;
#pragma unroll
    for (int i = 0; i < 6; ++i) {
        int sIdx = i * 256 + t;           // 0..1535
        int px = sIdx >> 4, seg = sIdx & 15;
        *(bf16x8*)(ob + px * 256 + seg * 8) =
            *(const bf16x8*)(&tile[px * 136 + seg * 8]);
    }
    bf16x8 z = {};
    if (t < 32) {                         // column halos (this c-half)
        int side = t >> 4, i = t & 15;
        *(bf16x8*)(xtp + ((size_t)(b * PW_ + h + 1) * PW_ + side * 97) * C_
                   + ch * 128 + i * 8) = z;
    }
    if (h == 0 || h == 95) {              // top/bottom halo rows, split by chalf
        int row = (h == 0) ? 0 : 97;
        __hip_bfloat16* rb = xtp + (size_t)(b * PW_ + row) * PROW_;
        for (int i = 0; i < 7; ++i) {
            int idx = i * 256 + t;        // 0..1567 of this half
            if (idx < 1568) *(bf16x8*)(rb + (ch * 1568 + idx) * 8) = z;
        }
    }
}

// ---------------------------------------------------------------------------
// offset conv via MFMA, K-split 2 halves + A staged in LDS (double-buffered,
// 1 barrier/tap). v2: w-split in half -> 768 blocks x 384 thr (6 waves =
// 3 w-tiles x 2 k-halves). v1's 384 blocks = 1.5 blocks/CU left half the
// CUs idle half the time; 768 = 3/CU exactly. A-stage traffic doubles but
// aOW (144KB) is L2-hot.
// ---------------------------------------------------------------------------
__global__ __launch_bounds__(384) void offset_conv_kernel(
    const __hip_bfloat16* __restrict__ xtp, const __hip_bfloat16* __restrict__ aOW,
    const float* __restrict__ bias, __hip_bfloat16* __restrict__ off2)
{
    int blk = blockIdx.x;                 // 0..767
    int xcd = blk & 7;
    int s   = blk >> 3;                   // 0..95
    int unit = xcd * 96 + s;              // XCD-chunked: neighbors share rows
    int bh   = unit >> 1;
    int whalf = unit & 1;
    int b   = bh / H_, h = bh % H_;
    int t = threadIdx.x, lane = t & 63;
    int ww = __builtin_amdgcn_readfirstlane(t >> 6);  // 0..5
    int nt = ww % 3;                      // w tile
    int kh = ww / 3;                      // k half
    int w0 = whalf * 48 + nt * 16;
    int ml = lane & 15, kq = lane >> 4;

    __shared__ __align__(16) __hip_bfloat16 aS[2][8192];   // per-tap A slice
    __shared__ __align__(16) f32x4 red[3 * 64 * 2];

    auto stage = [&](int tap, int p) {
        const bf16x8* src = (const bf16x8*)(aOW + tap * 8192);
        bf16x8* dst = (bf16x8*)aS[p];
        for (int i = t; i < 1024; i += 384) dst[i] = src[i];
    };

    f32x4 acc0 = {}, acc1 = {};
    const __hip_bfloat16* xb = xtp + (size_t)b * (PW_ * PROW_);

    stage(0, 0);
    __syncthreads();
    for (int tap = 0; tap < 9; ++tap) {
        if (tap < 8) stage(tap + 1, (tap + 1) & 1);   // loads issue early
        int ky = tap / 3, kx = tap - ky * 3;
        const __hip_bfloat16* brow =
            xb + ((h + ky) * PW_ + (w0 + ml + kx)) * C_ + kh * 128 + kq * 8;
        const __hip_bfloat16* arow = aS[tap & 1] + kh * 4096 + lane * 8;
#pragma unroll
        for (int ks = 0; ks < 4; ++ks) {
            bf16x8 bf = *(const bf16x8*)(brow + ks * 32);
            bf16x8 a0 = *(const bf16x8*)(arow + ks * 1024);
            bf16x8 a1 = *(const bf16x8*)(arow + ks * 1024 + 512);
            acc0 = __builtin_amdgcn_mfma_f32_16x16x32_bf16(a0, bf, acc0, 0, 0, 0);
            acc1 = __builtin_amdgcn_mfma_f32_16x16x32_bf16(a1, bf, acc1, 0, 0, 0);
        }
        __syncthreads();
    }

    // cross-half reduction in LDS
    if (kh == 1) {
        red[(nt * 64 + lane) * 2 + 0] = acc0;
        red[(nt * 64 + lane) * 2 + 1] = acc1;
    }
    __syncthreads();
    if (kh == 0) {
        acc0 += red[(nt * 64 + lane) * 2 + 0];
        acc1 += red[(nt * 64 + lane) * 2 + 1];
        // C/D: col=lane&15 -> w, row=kq*4+r -> out channel j
        int w = w0 + ml;
#pragma unroll
        for (int r = 0; r < 4; ++r) {
            int j0 = kq * 4 + r;
            off2[((size_t)(b * 9 + (j0 >> 1)) * HW_ + h * W_ + w) * 2 + (j0 & 1)] =
                __float2bfloat16(acc0[r] + bias[j0]);
            int j1 = 16 + kq * 4 + r;
            if (j1 < 18)
                off2[((size_t)(b * 9 + (j1 >> 1)) * HW_ + h * W_ + w) * 2 + (j1 & 1)] =
                    __float2bfloat16(acc1[r] + bias[j1]);
        }
    }
}

// ---------------------------------------------------------------------------
// deform conv via MFMA. v2 pipeline restructure: sample() split into
// gather() (addr/weight math + issue all 8 corner loads into registers) and
// finish() (wait, interpolate, LDS write), with mmtap(k) BETWEEN them so the
// ~200-400cy L2 gather latency hides under 16 MFMAs + ds_reads in-wave.
// Offsets prefetched one further tap ahead (kills offp->gather serial chain).
// v1 compiled to 40 VGPR = compiler had serialized load->interp->mfma
// (MfmaUtil 7.5%, VALUBusy 44%, ~50% stall). launch_bounds(384,6) pins
// VGPR<=~85 so 4 blocks/CU (24 waves) survive the added live corners.
// Interpolation expression per element kept identical (absmax at threshold).
// ---------------------------------------------------------------------------
__global__ __launch_bounds__(384, 6) void deform_kernel(
    const __hip_bfloat16* __restrict__ xtp, const __hip_bfloat16* __restrict__ off2,
    const __hip_bfloat16* __restrict__ aW, float* __restrict__ out)
{
    int blk = blockIdx.x;                 // 0..1535
    int xcd = blk & 7;
    int s   = blk >> 3;                   // 0..191
    int bg  = xcd * 2 + (s / H_);         // 0..15
    int h   = s % H_;
    int g   = bg & 3;
    int b   = bg >> 2;
    int t    = threadIdx.x;
    int lane = t & 63;
    int wave = __builtin_amdgcn_readfirstlane(t >> 6);  // 0..5
    int half   = wave & 1;                // co half (32)
    int wthird = wave >> 1;               // w third (32)

    __shared__ __align__(16) __hip_bfloat16 sS[2][96 * 72]; // [w][64c+pad]

    // interior origin: padded (1,1) == image (0,0)
    const __hip_bfloat16* xb =
        xtp + ((size_t)b * (PW_ * PW_) + PW_ + 1) * C_ + g * CG_;
    const __hip_bfloat162* offp =
        (const __hip_bfloat162*)off2 + (size_t)(b * 9) * HW_ + h * W_;
    const __hip_bfloat16* aWg = aW + (g * 9) * 4096;

    int tw8 = t >> 3;                     // 0..47
    int j8  = (t & 7) * 8;                // c offset within group

    f32x4 acc[2][2] = {};                 // [ct co16][wt w16]

    __hip_bfloat162 pr[2];                // prefetched offsets (next sample tap)
    bf16x8 c00[2], c01[2], c10[2], c11[2];
    float bw00[2], bw01[2], bw10[2], bw11[2];

    auto ld_off = [&](int k) {
#pragma unroll
        for (int it = 0; it < 2; ++it)
            pr[it] = offp[k * HW_ + it * 48 + tw8];
    };

    // addr + bilinear weights + ISSUE the 8 corner loads (no use yet)
    auto gather = [&](int k) {
        int ky = k / 3, kx = k - ky * 3;
#pragma unroll
        for (int it = 0; it < 2; ++it) {
            int w  = it * 48 + tw8;
            float py = (float)(h + ky - 1) + __bfloat162float(pr[it].x);
            float px = (float)(w + kx - 1) + __bfloat162float(pr[it].y);
            bool valid = (py > -1.f) && (py < (float)H_) &&
                         (px > -1.f) && (px < (float)W_);
            float y0f = floorf(py), x0f = floorf(px);
            float ly = py - y0f, lx = px - x0f;
            int y0 = (int)y0f, x0 = (int)x0f;
            // valid => all 4 corners inside padded image.
            // invalid => base -> padded (0,0) halo corner, weights zeroed.
            int base = valid ? (y0 * PW_ + x0) * C_ : -(PW_ + 1) * C_;
            float wy1 = valid ? ly : 0.f;
            float wy0 = valid ? (1.f - ly) : 0.f;
            float mx0 = 1.f - lx;
            bw00[it] = wy0 * mx0; bw01[it] = wy0 * lx;
            bw10[it] = wy1 * mx0; bw11[it] = wy1 * lx;
            const __hip_bfloat16* p0 = xb + base + j8;
            c00[it] = *(const bf16x8*)(p0);
            c01[it] = *(const bf16x8*)(p0 + C_);
            c10[it] = *(const bf16x8*)(p0 + PROW_);
            c11[it] = *(const bf16x8*)(p0 + PROW_ + C_);
        }
    };

    // consume loads: interpolate + LDS write (expression identical to v1)
    auto finish = [&](int p) {
#pragma unroll
        for (int it = 0; it < 2; ++it) {
            int w = it * 48 + tw8;
            bf16x8 r;
#pragma unroll
            for (int e = 0; e < 8; ++e) {
                float v = bw00[it] * (float)c00[it][e] + bw01[it] * (float)c01[it][e]
                        + bw10[it] * (float)c10[it][e] + bw11[it] * (float)c11[it][e];
                r[e] = (__bf16)v;
            }
            *(bf16x8*)(&sS[p][w * 72 + j8]) = r;
        }
    };

    auto mmtap = [&](int k, int p) {
        const __hip_bfloat16* at = aWg + k * 4096 + half * 1024 + lane * 8;
#pragma unroll
        for (int ks = 0; ks < 2; ++ks) {
            bf16x8 a0 = *(const bf16x8*)(at + ks * 2048);
            bf16x8 a1 = *(const bf16x8*)(at + ks * 2048 + 512);
#pragma unroll
            for (int wt = 0; wt < 2; ++wt) {
                int wrow = wthird * 32 + wt * 16 + (lane & 15);
                bf16x8 bfrag = *(const bf16x8*)(
                    &sS[p][wrow * 72 + ks * 32 + (lane >> 4) * 8]);
                acc[0][wt] = __builtin_amdgcn_mfma_f32_16x16x32_bf16(
                                 a0, bfrag, acc[0][wt], 0, 0, 0);
                acc[1][wt] = __builtin_amdgcn_mfma_f32_16x16x32_bf16(
                                 a1, bfrag, acc[1][wt], 0, 0, 0);
            }
        }
    };

    // prologue: tap 0 (latency exposed once), offsets for tap 1 prefetched
    ld_off(0);
    gather(0);
    ld_off(1);
    finish(0);
    __syncthreads();

#pragma unroll
    for (int k = 0; k < K_; ++k) {
        if (k < K_ - 1) {
            gather(k + 1);                 // 8 gathers in flight...
            if (k < K_ - 2) ld_off(k + 2); // ...plus next-tap offsets
        }
        mmtap(k, k & 1);                   // gathers hide under MFMA+ds_read
        if (k < K_ - 1) {
            finish((k + 1) & 1);
            __syncthreads();
        }
    }

    // epilogue: C/D layout col=lane&15 (w), row=(lane>>4)*4+reg (co)
    float* ob = out + ((b * C_ + g * CG_ + half * 32) * HW_) + h * W_ + wthird * 32;
    int rbase = (lane >> 4) * 4;
    int ncol  = lane & 15;
#pragma unroll
    for (int ct = 0; ct < 2; ++ct)
#pragma unroll
        for (int wt = 0; wt < 2; ++wt)
#pragma unroll
            for (int r = 0; r < 4; ++r)
                __builtin_nontemporal_store(
                    acc[ct][wt][r],
                    ob + (ct * 16 + rbase + r) * HW_ + wt * 16 + ncol);
}

// ---------------------------------------------------------------------------
extern "C" void kernel_launch(void* const* d_in, const int* in_sizes, int n_in,
                              void* d_out, int out_size, void* d_ws, size_t ws_size,
                              hipStream_t stream) {
    const float* x    = (const float*)d_in[0];
    const float* ow   = (const float*)d_in[1];   // offset_w (18,256,3,3)
    const float* obi  = (const float*)d_in[2];   // offset_b (18,)
    const float* wt   = (const float*)d_in[3];   // weight   (256,64,3,3)

    // ws: xtp bf16 padded (19.67MB) | off2 bf16 (1.33MB) | aW (0.29MB) | aOW (0.15MB)
    __hip_bfloat16* xtp  = (__hip_bfloat16*)d_ws;
    __hip_bfloat16* off2 = xtp + (size_t)B_ * PW_ * PW_ * C_;
    __hip_bfloat16* aW   = off2 + (size_t)B_ * 9 * HW_ * 2;
    __hip_bfloat16* aOW  = aW + 147456;

    prep_kernel<<<576, 256, 0, stream>>>(ow, wt, aOW, aW);
    transpose_kernel<<<B_ * H_ * 2, 256, 0, stream>>>(x, xtp);
    offset_conv_kernel<<<B_ * H_ * 2, 384, 0, stream>>>(xtp, aOW, obi, off2);
    deform_kernel<<<B_ * G_ * H_, 384, 0, stream>>>(xtp, off2, aW, (float*)d_out);
}